// Round 3
// baseline (377.812 us; speedup 1.0000x reference)
//
#include <hip/hip_runtime.h>
#include <stdint.h>

#define GENOMES 8
#define BATCH 2
#define SEQ 2048
#define EMBED 1024
#define KVD 256              // KV_HEADS * HEAD_DIM
#define M_PER_G (BATCH*SEQ)  // 4096

typedef float f32x4 __attribute__((ext_vector_type(4)));
typedef __bf16 bf16x8 __attribute__((ext_vector_type(8)));
typedef short s16x8 __attribute__((ext_vector_type(8)));
typedef short s16x4 __attribute__((ext_vector_type(4)));

static __device__ __forceinline__ unsigned short f2bf(float f) {
  unsigned int u = __builtin_bit_cast(unsigned int, f);
  u += 0x7FFFu + ((u >> 16) & 1u);   // round-to-nearest-even
  return (unsigned short)(u >> 16);
}

// async 16B global->LDS. LDS dest must be wave-uniform; HW writes base+lane*16.
static __device__ __forceinline__ void gll16(const void* g, void* l) {
  __builtin_amdgcn_global_load_lds(
      (const __attribute__((address_space(1))) unsigned int*)g,
      (__attribute__((address_space(3))) unsigned int*)l, 16, 0, 0);
}

#define WAITVM(n) asm volatile("s_waitcnt vmcnt(" #n ")" ::: "memory")
#define MEMFENCE() asm volatile("" ::: "memory")

// ---------------------------------------------------------------------------
// Wv (g, 1024, 256) fp32 -> Wv_bf (g, 1024, 256) bf16  (straight cast, no transpose:
// Wv is consumed as the B^T operand of the weight-fuse GEMM)
// ---------------------------------------------------------------------------
__global__ __launch_bounds__(256) void castwv_kernel(const float* __restrict__ Wv,
                                                     unsigned short* __restrict__ O) {
  size_t i = ((size_t)blockIdx.x * 256 + threadIdx.x) * 8;
  f32x4 a = *(const f32x4*)(Wv + i);
  f32x4 b = *(const f32x4*)(Wv + i + 4);
  s16x8 o;
  o[0] = (short)f2bf(a[0]); o[1] = (short)f2bf(a[1]);
  o[2] = (short)f2bf(a[2]); o[3] = (short)f2bf(a[3]);
  o[4] = (short)f2bf(b[0]); o[5] = (short)f2bf(b[1]);
  o[6] = (short)f2bf(b[2]); o[7] = (short)f2bf(b[3]);
  *(s16x8*)(O + i) = o;
}

// ---------------------------------------------------------------------------
// Wo (g, 1024, 1024) fp32 -> RT (g, 1024, 256) bf16
// RT[o][kh*64+d] = 64 * sum_{r=0..3} Wo[kh*256 + r*64 + d][o]
// (head-broadcast folded into Wo, x64 softmax-sum factor folded in, transposed)
// ---------------------------------------------------------------------------
__global__ __launch_bounds__(256) void rt_kernel(const float* __restrict__ Wo,
                                                 unsigned short* __restrict__ RT) {
  int g = blockIdx.y;
  int ot = blockIdx.x >> 2;          // 16 o-tiles of 64
  int kh = blockIdx.x & 3;           // 4 kv heads
  int o0 = ot * 64;
  const float* W = Wo + (size_t)g * EMBED * EMBED;
  unsigned short* T = RT + (size_t)g * EMBED * KVD;
  __shared__ float tl[64][65];
  int t = threadIdx.x;
  int rr = t >> 4;
  int cc = (t & 15) * 4;
#pragma unroll
  for (int p = 0; p < 4; ++p) {
    int d = rr + p * 16;
    float a0 = 0.f, a1 = 0.f, a2 = 0.f, a3 = 0.f;
#pragma unroll
    for (int r = 0; r < 4; ++r) {
      float4 v = *(const float4*)(W + (size_t)(kh * 256 + r * 64 + d) * EMBED + o0 + cc);
      a0 += v.x; a1 += v.y; a2 += v.z; a3 += v.w;
    }
    tl[d][cc + 0] = a0; tl[d][cc + 1] = a1; tl[d][cc + 2] = a2; tl[d][cc + 3] = a3;
  }
  __syncthreads();
#pragma unroll
  for (int p = 0; p < 4; ++p) {
    int o = rr + p * 16;
    s16x4 v;
    v[0] = (short)f2bf(64.f * tl[cc + 0][o]);
    v[1] = (short)f2bf(64.f * tl[cc + 1][o]);
    v[2] = (short)f2bf(64.f * tl[cc + 2][o]);
    v[3] = (short)f2bf(64.f * tl[cc + 3][o]);
    *(s16x4*)(T + (size_t)(o0 + o) * KVD + kh * 64 + cc) = v;
  }
}

// ---------------------------------------------------------------------------
// C[M,N] = A[M,K] * Bt[N,K]^T   (per genome in blockIdx.y)
// 128x128 tile, BK=32, 256 threads = 4 waves, wave owns a 64x64 quadrant
// (16 MFMA per K-step per wave). Depth-3 LDS ring, counted vmcnt (L in
// flight across the single per-iter s_barrier), stage issue after barrier
// into the slot read LAST iter (race-free by barrier ordering).
// ---------------------------------------------------------------------------
template <bool A_F32, bool OUT_BF16, int M, int N, int K>
__global__ __launch_bounds__(256) void gemm_bt(const void* __restrict__ Aall,
                                               const unsigned short* __restrict__ Btall,
                                               void* __restrict__ Call) {
  constexpr int BM = 128, BN = 128, BK = 32;
  constexpr int ABYTES = A_F32 ? BM * BK * 4 : BM * BK * 2;  // 16K or 8K
  constexpr int SB = ABYTES + BN * BK * 2;                   // +8K for B
  constexpr int NTN = N / BN;
  constexpr int NWG = (M / BM) * NTN;
  constexpr int NT = K / BK;
  static_assert(NWG % 8 == 0, "XCD swizzle needs nwg%8==0");
  static_assert(NT >= 3, "pipeline needs NT>=3");

  __shared__ __align__(16) unsigned char smem[3 * SB];       // 72K or 48K

  int g = blockIdx.y;
  int bid = blockIdx.x;
  // bijective XCD swizzle: each XCD gets a contiguous bm-major chunk so the
  // resident blocks of one XCD share few A panels (L2-resident working set).
  int lt = (bid & 7) * (NWG >> 3) + (bid >> 3);
  int bm = lt / NTN, bn = lt % NTN;
  int m0 = bm * BM, n0 = bn * BN;

  const unsigned short* Bt = Btall + (size_t)g * N * K;
  const float* Af = (const float*)Aall + (size_t)g * M * K;
  const unsigned short* Ab = (const unsigned short*)Aall + (size_t)g * M * K;

  int tid = threadIdx.x;
  int lane = tid & 63, wave = tid >> 6;
  int lm = lane & 15, quad = lane >> 4;
  int wm = (wave >> 1) * 64, wn = (wave & 1) * 64;

  // ---- per-thread pre-swizzled staging sources ----
  // f32 rows (128B = 8 chunks): data chunk c of row r stored at slot c ^ (r&7)
  // bf16 rows (64B = 4 chunks): data chunk c of row r stored at slot c ^ ((r>>1)&3)
  const float* srcAf = nullptr;
  const unsigned short* srcAb = nullptr;
  if constexpr (A_F32) {
    int rA = wave * 8 + (lane >> 3);
    int cA = (lane & 7) ^ (rA & 7);
    srcAf = Af + (size_t)(m0 + rA) * K + cA * 4;
  } else {
    int rA = wave * 32 + (lane >> 2);
    int cA = (lane & 3) ^ ((rA >> 1) & 3);
    srcAb = Ab + (size_t)(m0 + rA) * K + cA * 8;
  }
  int rB = wave * 32 + (lane >> 2);
  int cB = (lane & 3) ^ ((rB >> 1) & 3);
  const unsigned short* srcB = Bt + (size_t)(n0 + rB) * K + cB * 8;

  // ---- fragment LDS byte offsets (swizzled reads, within one stage buffer) ----
  int offA[4][2];
  int offB[4];
#pragma unroll
  for (int i = 0; i < 4; ++i) {
    if constexpr (A_F32) {
#pragma unroll
      for (int u = 0; u < 2; ++u)
        offA[i][u] = (wm + i * 16 + lm) * 128 + (((2 * quad + u) ^ (lm & 7)) * 16);
    } else {
      offA[i][0] = (wm + i * 16 + lm) * 64 + ((quad ^ ((lm >> 1) & 3)) * 16);
    }
  }
#pragma unroll
  for (int j = 0; j < 4; ++j)
    offB[j] = ABYTES + (wn + j * 16 + lm) * 64 + ((quad ^ ((lm >> 1) & 3)) * 16);

  f32x4 acc[4][4] = {};

  auto stage = [&](int slot, int t) {
    unsigned char* db = smem + slot * SB;
    if constexpr (A_F32) {
      const float* s = srcAf + (size_t)t * BK;
#pragma unroll
      for (int p = 0; p < 4; ++p)
        gll16(s + (size_t)p * 32 * K, db + wave * 1024 + p * 4096);
    } else {
      const unsigned short* s = srcAb + (size_t)t * BK;
#pragma unroll
      for (int p = 0; p < 2; ++p)
        gll16(s + (size_t)p * 16 * K, db + wave * 2048 + p * 1024);
    }
    const unsigned short* s = srcB + (size_t)t * BK;
#pragma unroll
    for (int p = 0; p < 2; ++p)
      gll16(s + (size_t)p * 16 * K, db + ABYTES + wave * 2048 + p * 1024);
  };

  // iter: read frags from slot rd, issue stage(t+2) into slot read last iter
  // (safe: this iter's barrier proved all waves finished reads of t-1), MFMA.
  auto iter_body = [&](int rd, int wr, int t) {
    const unsigned char* db = smem + rd * SB;
    bf16x8 a[4], b[4];
    if constexpr (A_F32) {
#pragma unroll
      for (int i = 0; i < 4; ++i) {
        f32x4 lo = *(const f32x4*)(db + offA[i][0]);
        f32x4 hi = *(const f32x4*)(db + offA[i][1]);
#pragma unroll
        for (int u = 0; u < 4; ++u) {
          a[i][u] = (__bf16)lo[u];
          a[i][4 + u] = (__bf16)hi[u];
        }
      }
    } else {
#pragma unroll
      for (int i = 0; i < 4; ++i)
        a[i] = __builtin_bit_cast(bf16x8, *(const s16x8*)(db + offA[i][0]));
    }
#pragma unroll
    for (int j = 0; j < 4; ++j)
      b[j] = __builtin_bit_cast(bf16x8, *(const s16x8*)(db + offB[j]));

    if (t + 2 < NT) stage(wr, t + 2);

#pragma unroll
    for (int i = 0; i < 4; ++i)
#pragma unroll
      for (int j = 0; j < 4; ++j)
        acc[i][j] = __builtin_amdgcn_mfma_f32_16x16x32_bf16(a[i], b[j], acc[i][j], 0, 0, 0);
  };

  // prologue: 2 stages in flight
  stage(0, 0);
  stage(1, 1);

  int rd = 0, wr = 2;
  for (int t = 0; t < NT - 1; ++t) {
    if constexpr (A_F32) WAITVM(6); else WAITVM(4);  // retire stage t, keep t+1
    __builtin_amdgcn_s_barrier();
    MEMFENCE();
    iter_body(rd, wr, t);
    rd = (rd == 2) ? 0 : rd + 1;
    wr = (wr == 2) ? 0 : wr + 1;
  }
  {  // last iter: full drain
    WAITVM(0);
    __builtin_amdgcn_s_barrier();
    MEMFENCE();
    iter_body(rd, wr, NT - 1);
  }

  // ---- epilogue: C/D layout col=lane&15, row=quad*4+reg ----
  if constexpr (OUT_BF16) {
    unsigned short* C = (unsigned short*)Call + (size_t)g * M * N;
#pragma unroll
    for (int i = 0; i < 4; ++i)
#pragma unroll
      for (int j = 0; j < 4; ++j)
#pragma unroll
        for (int r = 0; r < 4; ++r) {
          int mm = m0 + wm + i * 16 + quad * 4 + r;
          int nn = n0 + wn + j * 16 + lm;
          C[(size_t)mm * N + nn] = f2bf(acc[i][j][r]);
        }
  } else {
    float* C = (float*)Call + (size_t)g * M * N;
#pragma unroll
    for (int i = 0; i < 4; ++i)
#pragma unroll
      for (int j = 0; j < 4; ++j)
#pragma unroll
        for (int r = 0; r < 4; ++r) {
          int mm = m0 + wm + i * 16 + quad * 4 + r;
          int nn = n0 + wn + j * 16 + lm;
          C[(size_t)mm * N + nn] = acc[i][j][r];
        }
  }
}

// ---------------------------------------------------------------------------
extern "C" void kernel_launch(void* const* d_in, const int* in_sizes, int n_in,
                              void* d_out, int out_size, void* d_ws, size_t ws_size,
                              hipStream_t stream) {
  const float* tensor = (const float*)d_in[0];
  // d_in[1] = Wq, d_in[2] = Wk: dead code in the reference (the buggy einsum
  // contracts them out; softmax collapses to a uniform x64 factor)
  const float* Wv = (const float*)d_in[3];
  const float* Wo = (const float*)d_in[4];
  float* out = (float*)d_out;

  unsigned short* WvB  = (unsigned short*)d_ws;                      //  4 MB  Wv bf16
  unsigned short* RT   = WvB  + (size_t)GENOMES * EMBED * KVD;       //  4 MB
  unsigned short* Wful = RT   + (size_t)GENOMES * EMBED * KVD;       // 16 MB  fused weight

  // prep: cast Wv, fold+transpose/convert Wo
  castwv_kernel<<<dim3(GENOMES * EMBED * KVD / (256 * 8)), 256, 0, stream>>>(Wv, WvB);
  rt_kernel<<<dim3(64, GENOMES), 256, 0, stream>>>(Wo, RT);

  // weight-fuse GEMM: Wful[g][o][i] = sum_d RT[g][o][d] * WvB[g][i][d]
  // (out = tensor @ Wv' @ R  ==  tensor @ Wful^T, by associativity)
  gemm_bt<false, true, EMBED, EMBED, KVD>
      <<<dim3((EMBED / 128) * (EMBED / 128), GENOMES), 256, 0, stream>>>(RT, WvB, Wful);

  // main GEMM: out[g] (4096x1024 f32) = tensor[g] (4096x1024 f32->bf16) @ Wful^T
  gemm_bt<true, false, M_PER_G, EMBED, EMBED>
      <<<dim3((M_PER_G / 128) * (EMBED / 128), GENOMES), 256, 0, stream>>>(tensor, Wful, out);
}

// Round 4
// 325.947 us; speedup vs baseline: 1.1591x; 1.1591x over previous
//
#include <hip/hip_runtime.h>
#include <stdint.h>

#define GENOMES 8
#define BATCH 2
#define SEQ 2048
#define EMBED 1024
#define KVD 256              // KV_HEADS * HEAD_DIM
#define M_PER_G (BATCH*SEQ)  // 4096

typedef float f32x4 __attribute__((ext_vector_type(4)));
typedef __bf16 bf16x8 __attribute__((ext_vector_type(8)));
typedef short s16x8 __attribute__((ext_vector_type(8)));
typedef short s16x4 __attribute__((ext_vector_type(4)));

static __device__ __forceinline__ unsigned short f2bf(float f) {
  unsigned int u = __builtin_bit_cast(unsigned int, f);
  u += 0x7FFFu + ((u >> 16) & 1u);   // round-to-nearest-even
  return (unsigned short)(u >> 16);
}

// async 16B global->LDS. LDS dest must be wave-uniform; HW writes base+lane*16.
static __device__ __forceinline__ void gll16(const void* g, void* l) {
  __builtin_amdgcn_global_load_lds(
      (const __attribute__((address_space(1))) unsigned int*)g,
      (__attribute__((address_space(3))) unsigned int*)l, 16, 0, 0);
}

#define WAITVM(n) asm volatile("s_waitcnt vmcnt(" #n ")" ::: "memory")
#define MEMFENCE() asm volatile("" ::: "memory")

// ---------------------------------------------------------------------------
// Wv (g, 1024, 256) fp32  ->  WvT (g, 256, 1024) bf16   (B^T layout for GEMM1)
// ---------------------------------------------------------------------------
__global__ __launch_bounds__(256) void wvt_kernel(const float* __restrict__ Wv,
                                                  unsigned short* __restrict__ WvT) {
  int g = blockIdx.y;
  int it = blockIdx.x >> 2;          // 16 i-tiles of 64
  int ot = blockIdx.x & 3;           // 4 o-tiles of 64
  int i0 = it * 64, o0 = ot * 64;
  const float* W = Wv + (size_t)g * EMBED * KVD;
  unsigned short* T = WvT + (size_t)g * KVD * EMBED;
  __shared__ unsigned short tl[64][65];
  int t = threadIdx.x;
  int rr = t >> 4;            // 0..15
  int cc = (t & 15) * 4;      // 0..60
#pragma unroll
  for (int p = 0; p < 4; ++p) {
    int r = rr + p * 16;
    float4 v = *(const float4*)(W + (size_t)(i0 + r) * KVD + o0 + cc);
    tl[r][cc + 0] = f2bf(v.x);
    tl[r][cc + 1] = f2bf(v.y);
    tl[r][cc + 2] = f2bf(v.z);
    tl[r][cc + 3] = f2bf(v.w);
  }
  __syncthreads();
#pragma unroll
  for (int p = 0; p < 4; ++p) {
    int o = rr + p * 16;
    s16x4 v;
    v[0] = (short)tl[cc + 0][o];
    v[1] = (short)tl[cc + 1][o];
    v[2] = (short)tl[cc + 2][o];
    v[3] = (short)tl[cc + 3][o];
    *(s16x4*)(T + (size_t)(o0 + o) * EMBED + i0 + cc) = v;
  }
}

// ---------------------------------------------------------------------------
// Wo (g, 1024, 1024) fp32 -> RT (g, 1024, 256) bf16
// RT[o][kh*64+d] = 64 * sum_{r=0..3} Wo[kh*256 + r*64 + d][o]
// (head-broadcast folded into Wo, x64 softmax-sum factor folded in, transposed)
// ---------------------------------------------------------------------------
__global__ __launch_bounds__(256) void rt_kernel(const float* __restrict__ Wo,
                                                 unsigned short* __restrict__ RT) {
  int g = blockIdx.y;
  int ot = blockIdx.x >> 2;          // 16 o-tiles of 64
  int kh = blockIdx.x & 3;           // 4 kv heads
  int o0 = ot * 64;
  const float* W = Wo + (size_t)g * EMBED * EMBED;
  unsigned short* T = RT + (size_t)g * EMBED * KVD;
  __shared__ float tl[64][65];
  int t = threadIdx.x;
  int rr = t >> 4;
  int cc = (t & 15) * 4;
#pragma unroll
  for (int p = 0; p < 4; ++p) {
    int d = rr + p * 16;
    float a0 = 0.f, a1 = 0.f, a2 = 0.f, a3 = 0.f;
#pragma unroll
    for (int r = 0; r < 4; ++r) {
      float4 v = *(const float4*)(W + (size_t)(kh * 256 + r * 64 + d) * EMBED + o0 + cc);
      a0 += v.x; a1 += v.y; a2 += v.z; a3 += v.w;
    }
    tl[d][cc + 0] = a0; tl[d][cc + 1] = a1; tl[d][cc + 2] = a2; tl[d][cc + 3] = a3;
  }
  __syncthreads();
#pragma unroll
  for (int p = 0; p < 4; ++p) {
    int o = rr + p * 16;
    s16x4 v;
    v[0] = (short)f2bf(64.f * tl[cc + 0][o]);
    v[1] = (short)f2bf(64.f * tl[cc + 1][o]);
    v[2] = (short)f2bf(64.f * tl[cc + 2][o]);
    v[3] = (short)f2bf(64.f * tl[cc + 3][o]);
    *(s16x4*)(T + (size_t)(o0 + o) * KVD + kh * 64 + cc) = v;
  }
}

// ---------------------------------------------------------------------------
// C[M,N] = A[M,K] * Bt[N,K]^T   (per genome in blockIdx.y)
// 128x256 tile, 512 threads = 8 waves (2m x 4n), each wave a 64x64 quadrant.
// K staged in 32-wide HALF-TILES; depth-4 half-tile LDS ring; counted vmcnt
// (one future half-tile always in flight across the single per-half-iter
// s_barrier); slot reuse separated by TWO barriers. Staging via
// global_load_lds(16B) with pre-swizzled global sources; swizzled frag reads.
// ---------------------------------------------------------------------------
template <bool A_F32, bool OUT_BF16, int M, int N, int K>
__global__ __launch_bounds__(512) void gemm_bt(const void* __restrict__ Aall,
                                               const unsigned short* __restrict__ Btall,
                                               void* __restrict__ Call) {
  constexpr int BM = 128, BN = 256, BKH = 32;
  constexpr int ABH = A_F32 ? BM * BKH * 4 : BM * BKH * 2;   // 16K or 8K
  constexpr int SBH = ABH + BN * BKH * 2;                    // +16K for B
  constexpr int NTN = N / BN;
  constexpr int NWG = (M / BM) * NTN;
  constexpr int NTH = K / BKH;                               // 32 or 8
  static_assert(NWG % 8 == 0, "XCD swizzle needs nwg%8==0");
  static_assert(NTH >= 4, "pipeline needs NTH>=4");

  __shared__ __align__(16) unsigned char smem[4 * SBH];      // 128K or 96K

  int g = blockIdx.y;
  int bid = blockIdx.x;
  // bijective XCD swizzle: contiguous bm-major chunk per XCD (A-panel L2 reuse).
  int lt = (bid & 7) * (NWG >> 3) + (bid >> 3);
  int bm = lt / NTN, bn = lt % NTN;
  int m0 = bm * BM, n0 = bn * BN;

  const unsigned short* Bt = Btall + (size_t)g * N * K;
  const float* Af = (const float*)Aall + (size_t)g * M * K;
  const unsigned short* Ab = (const unsigned short*)Aall + (size_t)g * M * K;

  int tid = threadIdx.x;
  int lane = tid & 63, wave = tid >> 6;                      // wave 0..7
  int lm = lane & 15, quad = lane >> 4;
  int wm = (wave >> 2) * 64, wn = (wave & 3) * 64;           // 2m x 4n quadrants

  // ---- per-thread pre-swizzled staging sources ----
  // f32 rows (128B = 8 chunks): data chunk c of row r stored at LDS slot c ^ (r&7)
  // bf16 rows (64B = 4 chunks): data chunk c of row r stored at LDS slot c ^ ((r>>1)&3)
  // (row offsets inside one stage keep the XOR key invariant: +8 rows for f32,
  //  +16 rows for bf16 don't change r&7 / (r>>1)&3)
  const float* srcAf = nullptr;
  const unsigned short* srcAb = nullptr;
  if constexpr (A_F32) {
    int rA = wave * 16 + (lane >> 3);          // 2 glls cover 16 rows/wave
    int cA = (lane & 7) ^ (rA & 7);
    srcAf = Af + (size_t)(m0 + rA) * K + cA * 4;
  } else {
    int rA = wave * 16 + (lane >> 2);          // 1 gll covers 16 rows/wave
    int cA = (lane & 3) ^ ((rA >> 1) & 3);
    srcAb = Ab + (size_t)(m0 + rA) * K + cA * 8;
  }
  int rB = wave * 32 + (lane >> 2);            // 2 glls cover 32 rows/wave
  int cB = (lane & 3) ^ ((rB >> 1) & 3);
  const unsigned short* srcB = Bt + (size_t)(n0 + rB) * K + cB * 8;

  // ---- fragment LDS byte offsets (swizzled reads, within one half-tile slot) ----
  int offA[4][2];
  int offB[4];
#pragma unroll
  for (int i = 0; i < 4; ++i) {
    if constexpr (A_F32) {
#pragma unroll
      for (int u = 0; u < 2; ++u)
        offA[i][u] = (wm + i * 16 + lm) * 128 + (((2 * quad + u) ^ (lm & 7)) * 16);
    } else {
      offA[i][0] = (wm + i * 16 + lm) * 64 + ((quad ^ ((lm >> 1) & 3)) * 16);
    }
  }
#pragma unroll
  for (int j = 0; j < 4; ++j)
    offB[j] = ABH + (wn + j * 16 + lm) * 64 + ((quad ^ ((lm >> 1) & 3)) * 16);

  f32x4 acc[4][4] = {};

  auto stage = [&](int slot, int h) {
    unsigned char* db = smem + slot * SBH;
    if constexpr (A_F32) {
      const float* s = srcAf + (size_t)h * BKH;
      gll16(s, db + wave * 2048);
      gll16(s + (size_t)8 * K, db + wave * 2048 + 1024);
    } else {
      gll16(srcAb + (size_t)h * BKH, db + wave * 1024);
    }
    const unsigned short* s = srcB + (size_t)h * BKH;
    gll16(s, db + ABH + wave * 2048);
    gll16(s + (size_t)16 * K, db + ABH + wave * 2048 + 1024);
  };

  // half-iter h: read frags from slot h&3, issue stage(h+2) into slot (h+2)&3
  // (= slot (h-2)&3, whose reads finished before barrier(h-1): 2-barrier gap).
  auto iter_body = [&](int h) {
    const unsigned char* db = smem + (h & 3) * SBH;
    bf16x8 a[4], b[4];
    if constexpr (A_F32) {
#pragma unroll
      for (int i = 0; i < 4; ++i) {
        f32x4 lo = *(const f32x4*)(db + offA[i][0]);
        f32x4 hi = *(const f32x4*)(db + offA[i][1]);
#pragma unroll
        for (int u = 0; u < 4; ++u) {
          a[i][u] = (__bf16)lo[u];
          a[i][4 + u] = (__bf16)hi[u];
        }
      }
    } else {
#pragma unroll
      for (int i = 0; i < 4; ++i)
        a[i] = __builtin_bit_cast(bf16x8, *(const s16x8*)(db + offA[i][0]));
    }
#pragma unroll
    for (int j = 0; j < 4; ++j)
      b[j] = __builtin_bit_cast(bf16x8, *(const s16x8*)(db + offB[j]));

    if (h + 2 < NTH) stage((h + 2) & 3, h + 2);

#pragma unroll
    for (int i = 0; i < 4; ++i)
#pragma unroll
      for (int j = 0; j < 4; ++j)
        acc[i][j] = __builtin_amdgcn_mfma_f32_16x16x32_bf16(a[i], b[j], acc[i][j], 0, 0, 0);
  };

  // prologue: 2 half-tiles in flight
  stage(0, 0);
  stage(1, 1);

  for (int h = 0; h < NTH - 1; ++h) {
    // retire half-tile h, keep h+1 (L loads) in flight across the barrier
    if constexpr (A_F32) WAITVM(4); else WAITVM(3);
    __builtin_amdgcn_s_barrier();
    MEMFENCE();
    iter_body(h);
  }
  {  // last half-iter: full drain
    WAITVM(0);
    __builtin_amdgcn_s_barrier();
    MEMFENCE();
    iter_body(NTH - 1);
  }

  // ---- epilogue: C/D layout col=lane&15, row=quad*4+reg ----
  if constexpr (OUT_BF16) {
    unsigned short* C = (unsigned short*)Call + (size_t)g * M * N;
#pragma unroll
    for (int i = 0; i < 4; ++i)
#pragma unroll
      for (int j = 0; j < 4; ++j)
#pragma unroll
        for (int r = 0; r < 4; ++r) {
          int mm = m0 + wm + i * 16 + quad * 4 + r;
          int nn = n0 + wn + j * 16 + lm;
          C[(size_t)mm * N + nn] = f2bf(acc[i][j][r]);
        }
  } else {
    float* C = (float*)Call + (size_t)g * M * N;
#pragma unroll
    for (int i = 0; i < 4; ++i)
#pragma unroll
      for (int j = 0; j < 4; ++j)
#pragma unroll
        for (int r = 0; r < 4; ++r) {
          int mm = m0 + wm + i * 16 + quad * 4 + r;
          int nn = n0 + wn + j * 16 + lm;
          C[(size_t)mm * N + nn] = acc[i][j][r];
        }
  }
}

// ---------------------------------------------------------------------------
extern "C" void kernel_launch(void* const* d_in, const int* in_sizes, int n_in,
                              void* d_out, int out_size, void* d_ws, size_t ws_size,
                              hipStream_t stream) {
  const float* tensor = (const float*)d_in[0];
  // d_in[1] = Wq, d_in[2] = Wk: dead code in the reference (the buggy einsum
  // contracts them out; softmax collapses to a uniform x64 factor)
  const float* Wv = (const float*)d_in[3];
  const float* Wo = (const float*)d_in[4];
  float* out = (float*)d_out;

  unsigned short* WvT = (unsigned short*)d_ws;                       //  4 MB
  unsigned short* RT  = WvT + (size_t)GENOMES * KVD * EMBED;         //  4 MB
  unsigned short* V   = RT  + (size_t)GENOMES * EMBED * KVD;         // 16 MB

  // prep: transpose/convert Wv, fold+transpose/convert Wo
  wvt_kernel<<<dim3(64, GENOMES), 256, 0, stream>>>(Wv, WvT);
  rt_kernel<<<dim3(64, GENOMES), 256, 0, stream>>>(Wo, RT);

  // GEMM1: V[g] (4096x256 bf16) = tensor[g] (4096x1024 f32->bf16) @ WvT^T
  // BN=256=N: A read exactly once, 256 blocks = 1/CU
  gemm_bt<true, true, M_PER_G, KVD, EMBED>
      <<<dim3((M_PER_G / 128) * (KVD / 256), GENOMES), 512, 0, stream>>>(tensor, WvT, V);

  // GEMM2: out[g] (4096x1024 f32) = V[g] (4096x256 bf16) @ RT^T  (x64 folded in RT)
  gemm_bt<false, false, M_PER_G, EMBED, KVD>
      <<<dim3((M_PER_G / 128) * (EMBED / 256), GENOMES), 512, 0, stream>>>(V, RT, out);
}